// Round 16
// baseline (162.456 us; speedup 1.0000x reference)
//
#include <hip/hip_runtime.h>
#include <hip/hip_fp16.h>
#include <math.h>

typedef unsigned short u16;
typedef __attribute__((ext_vector_type(8))) _Float16 half8;
typedef __attribute__((ext_vector_type(4))) float f32x4;

#define ASLOT 4096    // 2-phase: 128x32 tile elems
#define SLOT  12288   // 2-phase ring slot elems (24KB)

__device__ __forceinline__ u16 f2h(float f){ __half h=__float2half(f); u16 r; __builtin_memcpy(&r,&h,2); return r; }
__device__ __forceinline__ float h2f(u16 u){ __half h; __builtin_memcpy(&h,&u,2); return __half2float(h); }

#define SYNC1 do{ __builtin_amdgcn_sched_barrier(0); __builtin_amdgcn_s_barrier(); \
    asm volatile("s_waitcnt lgkmcnt(0)" ::: "memory"); __builtin_amdgcn_sched_barrier(0); \
    __builtin_amdgcn_s_setprio(1); }while(0)
#define SYNC2 do{ __builtin_amdgcn_s_setprio(0); __builtin_amdgcn_sched_barrier(0); \
    __builtin_amdgcn_s_barrier(); }while(0)

// ================= 2-phase 128x256 core (lin_qk + av; proven R13) ===========
template<int ROWS>
__device__ __forceinline__ void stage_tile2(const u16* __restrict__ G, int rowbase, int ldg,
                                            int k0, u16* Ls, int tid){
#pragma unroll
    for (int p = 0; p < ROWS / 64; ++p){
        const int lin = tid + p * 256;
        const int row = lin >> 2;
        const int cg  = ((lin & 3) ^ ((row >> 1) & 3)) * 8;
        const u16* g = G + (size_t)(rowbase + row) * ldg + (k0 + cg);
        __builtin_amdgcn_global_load_lds(
            (__attribute__((address_space(1))) void*)g,
            (__attribute__((address_space(3))) void*)(Ls + (size_t)lin * 8), 16, 0, 0);
    }
}

// EPI: 0=f32 out, 1=f16 out, 5=centered K split (Kd + residual Krs).
// BIASM: 0=none, 1=col bias[c], 2=row bias[r].
template<int EPI, int BIASM>
__device__ __forceinline__ void gemm_core(
    const u16* __restrict__ A, const u16* __restrict__ B,
    const float* __restrict__ bias,
    float* __restrict__ of, u16* __restrict__ oh,
    const float* __restrict__ cm, u16* __restrict__ od,
    int by, int bx, int lda, int ldb, int ldc, int K, u16* sh)
{
    const int tid  = threadIdx.x;
    const int lane = tid & 63, wv = tid >> 6;
    const int wr = (wv >> 1) * 64;
    const int wc = (wv & 1) * 128;
    const int row0 = by * 128, col0 = bx * 256;
    const int lr = lane & 15, hi = lane >> 4;
    const int co = (hi ^ ((lr >> 1) & 3)) * 8;

    f32x4 acc[4][8];
#pragma unroll
    for (int m = 0; m < 4; m++)
#pragma unroll
        for (int n = 0; n < 8; n++) acc[m][n] = (f32x4){0.f, 0.f, 0.f, 0.f};

    auto stage_set = [&](int buf, int k0){
        u16* s = sh + buf * SLOT;
        stage_tile2<128>(A, row0, lda, k0, s, tid);
        stage_tile2<256>(B, col0, ldb, k0, s + ASLOT, tid);
    };

    const int NIT = K >> 5;
    stage_set(0, 0);
    stage_set(1, 32);
    int bufs = 2, bufr = 0;
    for (int t = 0; t < NIT; ++t){
        if (t + 2 < NIT){ stage_set(bufs, (t + 2) << 5); bufs = (bufs + 1 == 3) ? 0 : bufs + 1; }
        const int rem = NIT - 1 - t;
        if (rem >= 2)      asm volatile("s_waitcnt vmcnt(12)" ::: "memory");
        else if (rem == 1) asm volatile("s_waitcnt vmcnt(6)" ::: "memory");
        else               asm volatile("s_waitcnt vmcnt(0)" ::: "memory");
        __builtin_amdgcn_s_barrier();
        __builtin_amdgcn_sched_barrier(0);

        const u16* s = sh + bufr * SLOT;
        bufr = (bufr + 1 == 3) ? 0 : bufr + 1;

        half8 a[4], b[8];
#pragma unroll
        for (int m = 0; m < 4; m++) a[m] = *(const half8*)&s[(wr + m * 16 + lr) * 32 + co];
#pragma unroll
        for (int n = 0; n < 8; n++) b[n] = *(const half8*)&s[ASLOT + (wc + n * 16 + lr) * 32 + co];
#pragma unroll
        for (int m = 0; m < 4; m++)
#pragma unroll
            for (int n = 0; n < 8; n++)
                acc[m][n] = __builtin_amdgcn_mfma_f32_16x16x32_f16(a[m], b[n], acc[m][n], 0, 0, 0);
        __builtin_amdgcn_sched_barrier(0);
        __builtin_amdgcn_s_barrier();
    }

    // Epilogue. C/D frag mapping: col = lane&15, row = (lane>>4)*4 + reg.
    const int bbase = (row0 >> 10) << 10;
#pragma unroll
    for (int m = 0; m < 4; m++) {
        const int rb = row0 + wr + m * 16 + hi * 4;
#pragma unroll
        for (int n = 0; n < 8; n++) {
            const int c = col0 + wc + n * 16 + lr;
            const float bc = (BIASM == 1) ? bias[c] : 0.f;
            const float cmn = (EPI == 5) ? cm[bbase + c] : 0.f;
#pragma unroll
            for (int q = 0; q < 4; q++) {
                const int r = rb + q;
                float v = acc[m][n][q] + bc;
                if (BIASM == 2) v += bias[r];
                const size_t idx = (size_t)r * ldc + c;
                if (EPI == 0) of[idx] = v;
                else if (EPI == 1) oh[idx] = f2h(v);
                else {
                    const float d  = v - cmn;
                    const u16  dh = f2h(d);
                    oh[idx] = dh;
                    od[idx] = f2h(d - h2f(dh));
                }
            }
        }
    }
}

// ============== 8-phase 256x256 core (qkt_vt only; proven R14) ==============
// EPI: 0=f32 out, 1=f16 out. BIASM: 1=col, 2=row.
template<int EPI, int BIASM>
__device__ __forceinline__ void gemm8(
    const u16* __restrict__ A, const u16* __restrict__ B,
    const float* __restrict__ bias,
    float* __restrict__ of, u16* __restrict__ oh,
    int by, int bx, int lda, int ldb, int ldc, int K, u16* sh)
{
    const int tid  = threadIdx.x;
    const int lane = tid & 63, wv = tid >> 6;
    const int wr = (wv >> 2) * 128;
    const int wc = (wv & 3) * 64;
    const int row0 = by * 256, col0 = bx * 256;
    const int lr = lane & 15, hi = lane >> 4;

    f32x4 acc[8][4];
#pragma unroll
    for (int m = 0; m < 8; m++)
#pragma unroll
        for (int n = 0; n < 4; n++) acc[m][n] = (f32x4){0.f, 0.f, 0.f, 0.f};

    auto STG = [&](int op, int kt, int half){
        const u16* G = op ? B : A;
        const int  ld = op ? ldb : lda;
        const int  rb = (op ? col0 : row0) + half * 128;
        const int  k0 = kt << 6;
        u16* dst = sh + ((kt & 1) << 15) + (op << 14) + (half << 13);
#pragma unroll
        for (int p = 0; p < 2; ++p){
            const int lin = tid + p * 512;
            const int r   = lin >> 3;
            const int cg  = (lin & 7) ^ (r & 7);
            const u16* g = G + (size_t)(rb + r) * ld + k0 + cg * 8;
            __builtin_amdgcn_global_load_lds(
                (__attribute__((address_space(1))) void*)g,
                (__attribute__((address_space(3))) void*)(dst + (size_t)lin * 8), 16, 0, 0);
        }
    };
    auto LDA_ = [&](half8* a, int kt, int mh){
        const u16* base = sh + ((kt & 1) << 15) + ((wr >> 7) << 13);
#pragma unroll
        for (int mi = 0; mi < 4; ++mi)
#pragma unroll
            for (int ks = 0; ks < 2; ++ks){
                const int row = (mh * 4 + mi) * 16 + lr;
                a[mi * 2 + ks] = *(const half8*)&base[row * 64 + (((hi + ks * 4) ^ (lr & 7)) * 8)];
            }
    };
    auto LDB_ = [&](half8* b, int kt, int nh){
        const u16* base = sh + ((kt & 1) << 15) + 16384 + ((wc >> 7) << 13);
        const int wcl = wc & 127;
#pragma unroll
        for (int ni = 0; ni < 2; ++ni)
#pragma unroll
            for (int ks = 0; ks < 2; ++ks){
                const int row = wcl + (nh * 2 + ni) * 16 + lr;
                b[ni * 2 + ks] = *(const half8*)&base[row * 64 + (((hi + ks * 4) ^ (lr & 7)) * 8)];
            }
    };
    auto MM = [&](half8* a, half8* b, int mh, int nh){
#pragma unroll
        for (int mi = 0; mi < 4; ++mi)
#pragma unroll
            for (int ni = 0; ni < 2; ++ni)
#pragma unroll
                for (int ks = 0; ks < 2; ++ks)
                    acc[mh * 4 + mi][nh * 2 + ni] = __builtin_amdgcn_mfma_f32_16x16x32_f16(
                        a[mi * 2 + ks], b[ni * 2 + ks], acc[mh * 4 + mi][nh * 2 + ni], 0, 0, 0);
    };

    const int NKT = K >> 6, NIT = NKT >> 1;
    STG(0, 0, 0); STG(0, 0, 1); STG(1, 0, 0); STG(1, 0, 1);
    STG(1, 1, 0); STG(1, 1, 1); STG(0, 1, 0);
    asm volatile("s_waitcnt vmcnt(6)" ::: "memory");
    __builtin_amdgcn_s_barrier();

    half8 a[8], b0[4], b1[4];
    for (int i = 0; i < NIT; ++i){
        const int t0 = 2 * i, t1 = 2 * i + 1;
        const bool m0 = (t0 + 2 < NKT), m1 = (t1 + 2 < NKT);
        LDA_(a, t0, 0); LDB_(b0, t0, 0);
        STG(0, t1, 1);
        SYNC1; MM(a, b0, 0, 0); SYNC2;
        LDB_(b1, t0, 1);
        SYNC1; MM(a, b1, 0, 1); SYNC2;
        LDA_(a, t0, 1);
        if (m0) STG(1, t0 + 2, 0);
        SYNC1; MM(a, b1, 1, 1); SYNC2;
        if (m0) { STG(1, t0 + 2, 1); STG(0, t0 + 2, 0); }
        if (m0) asm volatile("s_waitcnt vmcnt(6)" ::: "memory");
        else    asm volatile("s_waitcnt vmcnt(0)" ::: "memory");
        SYNC1; MM(a, b0, 1, 0); SYNC2;
        LDA_(a, t1, 0); LDB_(b0, t1, 0);
        if (m0) STG(0, t0 + 2, 1);
        SYNC1; MM(a, b0, 0, 0); SYNC2;
        LDB_(b1, t1, 1);
        SYNC1; MM(a, b1, 0, 1); SYNC2;
        LDA_(a, t1, 1);
        if (m1) STG(1, t1 + 2, 0);
        SYNC1; MM(a, b1, 1, 1); SYNC2;
        if (m1) { STG(1, t1 + 2, 1); STG(0, t1 + 2, 0); }
        if (m1) asm volatile("s_waitcnt vmcnt(6)" ::: "memory");
        else    asm volatile("s_waitcnt vmcnt(0)" ::: "memory");
        SYNC1; MM(a, b0, 1, 0); SYNC2;
    }

#pragma unroll
    for (int m = 0; m < 8; m++){
        const int rb = row0 + wr + m * 16 + hi * 4;
#pragma unroll
        for (int n = 0; n < 4; n++){
            const int c = col0 + wc + n * 16 + lr;
            const float bc = (BIASM == 1) ? bias[c] : 0.f;
#pragma unroll
            for (int q = 0; q < 4; q++){
                const int r = rb + q;
                float v = acc[m][n][q] + bc;
                if (BIASM == 2) v += bias[r];
                const size_t idx = (size_t)r * ldc + c;
                if (EPI == 0) of[idx] = v;
                else oh[idx] = f2h(v);
            }
        }
    }
}

// Fused Q + K linears, 2-phase (proven 57us): 512 blocks x 256 thr.
__global__ __launch_bounds__(256, 2) void lin_qk_k(
    const u16* __restrict__ rc_h, const u16* __restrict__ ri_h,
    const u16* __restrict__ Wq_h, const u16* __restrict__ Wk_h,
    const float* __restrict__ bq, const float* __restrict__ bk,
    const float* __restrict__ cm,
    u16* __restrict__ Q_h, u16* __restrict__ Kd, u16* __restrict__ Krs)
{
    __shared__ __align__(16) u16 sh[3 * SLOT];   // 72KB
    const int nwg = gridDim.x, chunk = nwg >> 3;
    const int swz = ((int)blockIdx.x & 7) * chunk + ((int)blockIdx.x >> 3);
    const int p = swz & 1, t = swz >> 1;
    if (p == 0) {
        gemm_core<1, 1>(rc_h, Wq_h, bq, nullptr, Q_h, nullptr, nullptr,
                        t >> 2, t & 3, 1024, 1024, 1024, 1024, sh);
    } else {
        gemm_core<5, 1>(ri_h, Wk_h, bk, nullptr, Kd, cm, Krs,
                        t >> 2, t & 3, 1024, 1024, 1024, 1024, sh);
    }
}

// Fused batched centered QK^T + V^T linear, 8-phase (proven R14): 256 x 512 thr.
__global__ __launch_bounds__(512, 1) void qkt_vt_k(
    const u16* __restrict__ Q_h, const u16* __restrict__ Kd,
    const u16* __restrict__ ri_h, const u16* __restrict__ Wv_h,
    const float* __restrict__ bv, const float* __restrict__ u,
    float* __restrict__ wts, u16* __restrict__ Vt)
{
    __shared__ __align__(16) u16 sh[65536];      // 128KB
    const int nwg = gridDim.x, chunk = nwg >> 3;
    const int swz = ((int)blockIdx.x & 7) * chunk + ((int)blockIdx.x >> 3);
    const int p = swz & 1, t = swz >> 1;
    if (p == 0) {   // S[b] = Q[b] @ Kd[b]^T + u[b] row-bias -> f32 logits
        const int z = t >> 4, rem = t & 15;
        gemm8<0, 2>(Q_h + ((size_t)z << 20), Kd + ((size_t)z << 20),
                    u + ((size_t)z << 10), wts + ((size_t)z << 20), nullptr,
                    rem >> 2, rem & 3, 1024, 1024, 1024, 1024, sh);
    } else {        // V^T = Wv @ ri^T + bv(row) -> [1024][8192]
        gemm8<1, 2>(Wv_h, ri_h, bv, nullptr, Vt,
                    t >> 5, t & 31, 1024, 1024, 8192, 1024, sh);
    }
}

// Batched AV, 2-phase: 256 blocks x 256 thr.
__global__ __launch_bounds__(256, 2) void av_k(
    const u16* __restrict__ W_h, const u16* __restrict__ Vt, float* __restrict__ outp)
{
    __shared__ __align__(16) u16 sh[3 * SLOT];   // 72KB
    const int nwg = gridDim.x, chunk = nwg >> 3;
    const int wg = ((int)blockIdx.x & 7) * chunk + ((int)blockIdx.x >> 3);
    const int z = wg >> 5, rem = wg & 31;
    gemm_core<0, 0>(W_h + ((size_t)z << 20), Vt + (size_t)z * 1024,
                    nullptr, outp + ((size_t)z << 20), nullptr, nullptr, nullptr,
                    rem >> 2, rem & 3, 1024, 8192, 1024, 1024, sh);
}

// ========================= small kernels ====================================
__global__ __launch_bounds__(256)
void colmean_k(const u16* __restrict__ ri_h, float* __restrict__ xbar)
{
    const int b = blockIdx.x >> 5, sub = blockIdx.x & 31;
    const int dg = sub & 3, rg = sub >> 2;
    const int d = dg * 256 + threadIdx.x;
    const u16* base = ri_h + ((size_t)b << 20) + ((size_t)(rg * 128) << 10) + d;
    float s = 0.f;
#pragma unroll 4
    for (int r = 0; r < 128; ++r) s += h2f(base[(size_t)r << 10]);
    atomicAdd(&xbar[(b << 10) + d], s * (1.f / 1024.f));
}

template<bool BIAS, bool AFULL>
__global__ __launch_bounds__(256)
void rowdot_k(const u16* __restrict__ A, const float* __restrict__ B,
              const float* __restrict__ bias, float* __restrict__ out)
{
    const int o = blockIdx.x * 4 + (threadIdx.x >> 6);
    const int lane = threadIdx.x & 63;
    const int ar = AFULL ? o : (o & 1023);
    const int br = o >> 10;
    const u16* ap = A + ((size_t)ar << 10);
    const float* bp = B + ((size_t)br << 10);
    float s = 0.f;
#pragma unroll
    for (int j = 0; j < 16; ++j){ const int i = lane + (j << 6); s += h2f(ap[i]) * bp[i]; }
#pragma unroll
    for (int off = 32; off >= 1; off >>= 1) s += __shfl_xor(s, off);
    if (lane == 0) out[o] = s + (BIAS ? bias[ar] : 0.f);
}

// Fused scale (x *= rsqrt(Kd+Krs+cm)) + row softmax + f16 weights copy (R14).
__global__ __launch_bounds__(256)
void softmax_scale_k(float* __restrict__ W, const u16* __restrict__ Kd,
                     const u16* __restrict__ Krs, const float* __restrict__ cm,
                     u16* __restrict__ Wh)
{
    const long row = blockIdx.x;
    const int b = (int)(row >> 10);
    float* p = W + (row << 10);
    const int tid = threadIdx.x;

    float4 v = ((const float4*)p)[tid];
    const ushort4 kd = ((const ushort4*)(Kd + (row << 10)))[tid];
    const ushort4 ks = ((const ushort4*)(Krs + (row << 10)))[tid];
    const float4 cmv = ((const float4*)(cm + ((size_t)b << 10)))[tid];
    v.x *= rsqrtf(h2f(kd.x) + h2f(ks.x) + cmv.x);
    v.y *= rsqrtf(h2f(kd.y) + h2f(ks.y) + cmv.y);
    v.z *= rsqrtf(h2f(kd.z) + h2f(ks.z) + cmv.z);
    v.w *= rsqrtf(h2f(kd.w) + h2f(ks.w) + cmv.w);

    float m = fmaxf(fmaxf(v.x, v.y), fmaxf(v.z, v.w));
#pragma unroll
    for (int o = 32; o >= 1; o >>= 1) m = fmaxf(m, __shfl_xor(m, o));
    __shared__ float sm[4];
    const int wid = tid >> 6, lane = tid & 63;
    if (lane == 0) sm[wid] = m;
    __syncthreads();
    m = fmaxf(fmaxf(sm[0], sm[1]), fmaxf(sm[2], sm[3]));

    v.x = __expf(v.x - m); v.y = __expf(v.y - m);
    v.z = __expf(v.z - m); v.w = __expf(v.w - m);
    float s = v.x + v.y + v.z + v.w;
#pragma unroll
    for (int o = 32; o >= 1; o >>= 1) s += __shfl_xor(s, o);
    __shared__ float ss[4];
    if (lane == 0) ss[wid] = s;
    __syncthreads();
    s = ss[0] + ss[1] + ss[2] + ss[3];

    const float inv = 1.0f / s;
    v.x *= inv; v.y *= inv; v.z *= inv; v.w *= inv;
    ((float4*)p)[tid] = v;

    ushort4 ub;
    ub.x = f2h(v.x); ub.y = f2h(v.y); ub.z = f2h(v.z); ub.w = f2h(v.w);
    ((ushort4*)(Wh + (row << 10)))[tid] = ub;
}

__global__ __launch_bounds__(256)
void conv_plain5_k(const float4* __restrict__ x0, ushort4* __restrict__ y0,
                   const float4* __restrict__ x1, ushort4* __restrict__ y1,
                   const float4* __restrict__ x2, ushort4* __restrict__ y2,
                   const float4* __restrict__ x3, ushort4* __restrict__ y3,
                   const float4* __restrict__ x4, ushort4* __restrict__ y4)
{
    const long i = (long)blockIdx.x * 256 + threadIdx.x;
    const long n0 = 2097152, n1 = 262144;
    const float4* x; ushort4* y; long j;
    if (i < n0)                 { x = x0; y = y0; j = i; }
    else if (i < 2*n0)          { x = x1; y = y1; j = i - n0; }
    else if (i < 2*n0 + n1)     { x = x2; y = y2; j = i - 2*n0; }
    else if (i < 2*n0 + 2*n1)   { x = x3; y = y3; j = i - 2*n0 - n1; }
    else                        { x = x4; y = y4; j = i - 2*n0 - 2*n1; }
    const float4 v = x[j];
    ushort4 o;
    o.x = f2h(v.x); o.y = f2h(v.y); o.z = f2h(v.z); o.w = f2h(v.w);
    y[j] = o;
}

extern "C" void kernel_launch(void* const* d_in, const int* in_sizes, int n_in,
                              void* d_out, int out_size, void* d_ws, size_t ws_size,
                              hipStream_t stream)
{
    const float* rc = (const float*)d_in[0];
    const float* ri = (const float*)d_in[1];
    const float* Wq = (const float*)d_in[3];
    const float* bq = (const float*)d_in[4];
    const float* Wk = (const float*)d_in[5];
    const float* bk = (const float*)d_in[6];
    const float* Wv = (const float*)d_in[7];
    const float* bv = (const float*)d_in[8];

    const long M8 = 8192 * 1024L;
    const long M1 = 1024 * 1024L;

    u16* ws   = (u16*)d_ws;
    u16* ri_h = ws;                  // 8M; reused as W_h after softmax
    u16* rc_h = ws + 1 * M8;         // 8M; reused as Vt after lin_qk
    u16* Kd   = ws + 2 * M8;         // 8M: centered K f16
    u16* Krs  = ws + 3 * M8;         // 8M: residual f16
    u16* Wq_h = ws + 4 * M8;         // 1M
    u16* Wk_h = Wq_h + M1;           // 1M
    u16* Wv_h = Wk_h + M1;           // 1M
    float* xbar = (float*)(ws + 4 * M8 + 3 * M1);
    float* cm   = xbar + 8192;
    float* uu   = cm + 8192;

    float* outp = (float*)d_out;
    float* wts  = outp + M8;
    u16*   Q_h  = (u16*)d_out;       // scratch in outp half, dead before AV
    u16*   Vt   = rc_h;              // V^T [1024][8192]
    u16*   W_h  = ri_h;

    conv_plain5_k<<<19456, 256, 0, stream>>>(
        (const float4*)ri, (ushort4*)ri_h, (const float4*)rc, (ushort4*)rc_h,
        (const float4*)Wq, (ushort4*)Wq_h, (const float4*)Wk, (ushort4*)Wk_h,
        (const float4*)Wv, (ushort4*)Wv_h);

    hipMemsetAsync(xbar, 0, 8192 * sizeof(float), stream);
    colmean_k<<<256, 256, 0, stream>>>(ri_h, xbar);
    rowdot_k<true, false><<<2048, 256, 0, stream>>>(Wk_h, xbar, bk, cm);

    // Q + K linears, 2-phase (proven): 512 blocks x 256 thr
    lin_qk_k<<<512, 256, 0, stream>>>(rc_h, ri_h, Wq_h, Wk_h, bq, bk, cm, Q_h, Kd, Krs);

    rowdot_k<false, true><<<2048, 256, 0, stream>>>(Q_h, cm, nullptr, uu);

    // centered QK^T + V^T, 8-phase (proven R14): 256 blocks x 512 thr
    qkt_vt_k<<<256, 512, 0, stream>>>(Q_h, Kd, ri_h, Wv_h, bv, uu, wts, Vt);

    // scale by rsqrt(K) + softmax + f16 weights copy
    softmax_scale_k<<<8192, 256, 0, stream>>>(wts, Kd, Krs, cm, W_h);

    // output = weights @ V, 2-phase
    av_k<<<256, 256, 0, stream>>>(W_h, Vt, outp);
}

// Round 17
// 157.827 us; speedup vs baseline: 1.0293x; 1.0293x over previous
//
#include <hip/hip_runtime.h>
#include <hip/hip_fp16.h>
#include <math.h>

typedef unsigned short u16;
typedef __attribute__((ext_vector_type(8))) _Float16 half8;
typedef __attribute__((ext_vector_type(4))) float f32x4;

#define ASLOT 4096    // 2-phase: 128x32 tile elems
#define SLOT  12288   // 2-phase ring slot elems

__device__ __forceinline__ u16 f2h(float f){ __half h=__float2half(f); u16 r; __builtin_memcpy(&r,&h,2); return r; }
__device__ __forceinline__ float h2f(u16 u){ __half h; __builtin_memcpy(&h,&u,2); return __half2float(h); }

#define SYNC1 do{ __builtin_amdgcn_sched_barrier(0); __builtin_amdgcn_s_barrier(); \
    asm volatile("s_waitcnt lgkmcnt(0)" ::: "memory"); __builtin_amdgcn_sched_barrier(0); \
    __builtin_amdgcn_s_setprio(1); }while(0)
#define SYNC2 do{ __builtin_amdgcn_s_setprio(0); __builtin_amdgcn_sched_barrier(0); \
    __builtin_amdgcn_s_barrier(); }while(0)

// ======================= 8-phase 256x256 core (T2+T3+T4+T5) =================
// 8 waves (512 thr), BK=64, per-wave 128x64 acc (acc[8][4]). LDS 128KB.
// Stage plan + vmcnt(6) liveness as verified in R14. Congruent 256-block
// grids for lin_qk and qkt_vt keep producer->consumer tiles in the same
// XCD's L2 (cross-launch T1 locality).
// EPI: 0=f32, 1=f16, 5=centered split. BIASM: 0 none, 1 col, 2 row.
template<int EPI, int BIASM>
__device__ __forceinline__ void gemm8(
    const u16* __restrict__ A, const u16* __restrict__ B,
    const float* __restrict__ bias,
    float* __restrict__ of, u16* __restrict__ oh,
    const float* __restrict__ cm, u16* __restrict__ od,
    int by, int bx, int lda, int ldb, int ldc, int K, u16* sh)
{
    const int tid  = threadIdx.x;
    const int lane = tid & 63, wv = tid >> 6;
    const int wr = (wv >> 2) * 128;      // 2 M-groups
    const int wc = (wv & 3) * 64;        // 4 N-groups
    const int row0 = by * 256, col0 = bx * 256;
    const int lr = lane & 15, hi = lane >> 4;

    f32x4 acc[8][4];
#pragma unroll
    for (int m = 0; m < 8; m++)
#pragma unroll
        for (int n = 0; n < 4; n++) acc[m][n] = (f32x4){0.f, 0.f, 0.f, 0.f};

    auto STG = [&](int op, int kt, int half){
        const u16* G = op ? B : A;
        const int  ld = op ? ldb : lda;
        const int  rb = (op ? col0 : row0) + half * 128;
        const int  k0 = kt << 6;
        u16* dst = sh + ((kt & 1) << 15) + (op << 14) + (half << 13);
#pragma unroll
        for (int p = 0; p < 2; ++p){
            const int lin = tid + p * 512;
            const int r   = lin >> 3;                 // 0..127
            const int cg  = (lin & 7) ^ (r & 7);      // pre-swizzled source chunk
            const u16* g = G + (size_t)(rb + r) * ld + k0 + cg * 8;
            __builtin_amdgcn_global_load_lds(
                (__attribute__((address_space(1))) void*)g,
                (__attribute__((address_space(3))) void*)(dst + (size_t)lin * 8), 16, 0, 0);
        }
    };
    auto LDA_ = [&](half8* a, int kt, int mh){
        const u16* base = sh + ((kt & 1) << 15) + ((wr >> 7) << 13);
#pragma unroll
        for (int mi = 0; mi < 4; ++mi)
#pragma unroll
            for (int ks = 0; ks < 2; ++ks){
                const int row = (mh * 4 + mi) * 16 + lr;          // within half
                a[mi * 2 + ks] = *(const half8*)&base[row * 64 + (((hi + ks * 4) ^ (lr & 7)) * 8)];
            }
    };
    auto LDB_ = [&](half8* b, int kt, int nh){
        const u16* base = sh + ((kt & 1) << 15) + 16384 + ((wc >> 7) << 13);
        const int wcl = wc & 127;
#pragma unroll
        for (int ni = 0; ni < 2; ++ni)
#pragma unroll
            for (int ks = 0; ks < 2; ++ks){
                const int row = wcl + (nh * 2 + ni) * 16 + lr;
                b[ni * 2 + ks] = *(const half8*)&base[row * 64 + (((hi + ks * 4) ^ (lr & 7)) * 8)];
            }
    };
    auto MM = [&](half8* a, half8* b, int mh, int nh){
#pragma unroll
        for (int mi = 0; mi < 4; ++mi)
#pragma unroll
            for (int ni = 0; ni < 2; ++ni)
#pragma unroll
                for (int ks = 0; ks < 2; ++ks)
                    acc[mh * 4 + mi][nh * 2 + ni] = __builtin_amdgcn_mfma_f32_16x16x32_f16(
                        a[mi * 2 + ks], b[ni * 2 + ks], acc[mh * 4 + mi][nh * 2 + ni], 0, 0, 0);
    };

    const int NKT = K >> 6, NIT = NKT >> 1;
    // prologue: KT0 fully + KT1 {Bh0,Bh1,Ah0}; drain KT0, keep 3 half-tiles
    STG(0, 0, 0); STG(0, 0, 1); STG(1, 0, 0); STG(1, 0, 1);
    STG(1, 1, 0); STG(1, 1, 1); STG(0, 1, 0);
    asm volatile("s_waitcnt vmcnt(6)" ::: "memory");
    __builtin_amdgcn_s_barrier();

    half8 a[8], b0[4], b1[4];
    for (int i = 0; i < NIT; ++i){
        const int t0 = 2 * i, t1 = 2 * i + 1;
        const bool m0 = (t0 + 2 < NKT), m1 = (t1 + 2 < NKT);
        // ph1
        LDA_(a, t0, 0); LDB_(b0, t0, 0);
        STG(0, t1, 1);                                  // A(t1)h1 completes buf1
        SYNC1; MM(a, b0, 0, 0); SYNC2;
        // ph2
        LDB_(b1, t0, 1);
        SYNC1; MM(a, b1, 0, 1); SYNC2;
        // ph3
        LDA_(a, t0, 1);
        if (m0) STG(1, t0 + 2, 0);
        SYNC1; MM(a, b1, 1, 1); SYNC2;
        // ph4
        if (m0) { STG(1, t0 + 2, 1); STG(0, t0 + 2, 0); }
        if (m0) asm volatile("s_waitcnt vmcnt(6)" ::: "memory");
        else    asm volatile("s_waitcnt vmcnt(0)" ::: "memory");
        SYNC1; MM(a, b0, 1, 0); SYNC2;
        // ph5
        LDA_(a, t1, 0); LDB_(b0, t1, 0);
        if (m0) STG(0, t0 + 2, 1);
        SYNC1; MM(a, b0, 0, 0); SYNC2;
        // ph6
        LDB_(b1, t1, 1);
        SYNC1; MM(a, b1, 0, 1); SYNC2;
        // ph7
        LDA_(a, t1, 1);
        if (m1) STG(1, t1 + 2, 0);
        SYNC1; MM(a, b1, 1, 1); SYNC2;
        // ph8
        if (m1) { STG(1, t1 + 2, 1); STG(0, t1 + 2, 0); }
        if (m1) asm volatile("s_waitcnt vmcnt(6)" ::: "memory");
        else    asm volatile("s_waitcnt vmcnt(0)" ::: "memory");
        SYNC1; MM(a, b0, 1, 0); SYNC2;
    }

    // Epilogue. C/D frag mapping: col = lane&15, row = (lane>>4)*4 + reg.
#pragma unroll
    for (int m = 0; m < 8; m++){
        const int rb = row0 + wr + m * 16 + hi * 4;
#pragma unroll
        for (int n = 0; n < 4; n++){
            const int c = col0 + wc + n * 16 + lr;
            const float bc = (BIASM == 1) ? bias[c] : 0.f;
            const float cmn = (EPI == 5) ? cm[(((row0 >> 10) << 10)) + c] : 0.f;
#pragma unroll
            for (int q = 0; q < 4; q++){
                const int r = rb + q;
                float v = acc[m][n][q] + bc;
                if (BIASM == 2) v += bias[r];
                const size_t idx = (size_t)r * ldc + c;
                if (EPI == 0) of[idx] = v;
                else if (EPI == 1) oh[idx] = f2h(v);
                else {
                    const float d  = v - cmn;
                    const u16  dh = f2h(d);
                    oh[idx] = dh;
                    od[idx] = f2h(d - h2f(dh));
                }
            }
        }
    }
}

// Fused Q + K linears, 8-phase, product-interleaved: 256 blocks x 512 thr.
// Grid/swizzle congruent with qkt_vt_k -> producer tiles stay in consumer's XCD L2.
__global__ __launch_bounds__(512, 1) void lin_qk_k(
    const u16* __restrict__ rc_h, const u16* __restrict__ ri_h,
    const u16* __restrict__ Wq_h, const u16* __restrict__ Wk_h,
    const float* __restrict__ bq, const float* __restrict__ bk,
    const float* __restrict__ cm,
    u16* __restrict__ Q_h, u16* __restrict__ Kd, u16* __restrict__ Krs)
{
    __shared__ __align__(16) u16 sh[65536];      // 128KB
    const int nwg = gridDim.x, chunk = nwg >> 3;
    const int swz = ((int)blockIdx.x & 7) * chunk + ((int)blockIdx.x >> 3);
    const int p = swz & 1, t = swz >> 1;         // t in [0,128): by<32, bx<4
    if (p == 0) {
        gemm8<1, 1>(rc_h, Wq_h, bq, nullptr, Q_h, nullptr, nullptr,
                    t >> 2, t & 3, 1024, 1024, 1024, 1024, sh);
    } else {
        gemm8<5, 1>(ri_h, Wk_h, bk, nullptr, Kd, cm, Krs,
                    t >> 2, t & 3, 1024, 1024, 1024, 1024, sh);
    }
}

// Fused batched centered QK^T + V^T linear, 8-phase: 256 blocks x 512 thr.
__global__ __launch_bounds__(512, 1) void qkt_vt_k(
    const u16* __restrict__ Q_h, const u16* __restrict__ Kd,
    const u16* __restrict__ ri_h, const u16* __restrict__ Wv_h,
    const float* __restrict__ bv, const float* __restrict__ u,
    float* __restrict__ wts, u16* __restrict__ Vt)
{
    __shared__ __align__(16) u16 sh[65536];
    const int nwg = gridDim.x, chunk = nwg >> 3;
    const int swz = ((int)blockIdx.x & 7) * chunk + ((int)blockIdx.x >> 3);
    const int p = swz & 1, t = swz >> 1;
    if (p == 0) {   // S[b] = Q[b] @ Kd[b]^T + u[b] row-bias
        const int z = t >> 4, rem = t & 15;      // by<4, bx<4
        gemm8<0, 2>(Q_h + ((size_t)z << 20), Kd + ((size_t)z << 20),
                    u + ((size_t)z << 10), wts + ((size_t)z << 20), nullptr,
                    nullptr, nullptr,
                    rem >> 2, rem & 3, 1024, 1024, 1024, 1024, sh);
    } else {        // V^T = Wv @ ri^T + bv(row) -> [1024][8192]
        gemm8<1, 2>(Wv_h, ri_h, bv, nullptr, Vt, nullptr, nullptr,
                    t >> 5, t & 31, 1024, 1024, 8192, 1024, sh);
    }
}

// ======================= 2-phase 128x256 core (for AV) ======================
__device__ __forceinline__ void stage_tile2(const u16* __restrict__ G, int rowbase, int ldg,
                                            int k0, u16* Ls, int tid, int rows){
    for (int p = 0; p < rows / 64; ++p){
        const int lin = tid + p * 256;
        const int row = lin >> 2;
        const int cg  = ((lin & 3) ^ ((row >> 1) & 3)) * 8;
        const u16* g = G + (size_t)(rowbase + row) * ldg + (k0 + cg);
        __builtin_amdgcn_global_load_lds(
            (__attribute__((address_space(1))) void*)g,
            (__attribute__((address_space(3))) void*)(Ls + (size_t)lin * 8), 16, 0, 0);
    }
}

__device__ __forceinline__ void gemm_core2(
    const u16* __restrict__ A, const u16* __restrict__ B,
    float* __restrict__ of,
    int by, int bx, int lda, int ldb, int ldc, int K, u16* sh)
{
    const int tid  = threadIdx.x;
    const int lane = tid & 63, wv = tid >> 6;
    const int wr = (wv >> 1) * 64;
    const int wc = (wv & 1) * 128;
    const int row0 = by * 128, col0 = bx * 256;
    const int lr = lane & 15, hi = lane >> 4;
    const int co = (hi ^ ((lr >> 1) & 3)) * 8;

    f32x4 acc[4][8];
#pragma unroll
    for (int m = 0; m < 4; m++)
#pragma unroll
        for (int n = 0; n < 8; n++) acc[m][n] = (f32x4){0.f, 0.f, 0.f, 0.f};

    auto stage_set = [&](int buf, int k0){
        u16* s = sh + buf * SLOT;
        stage_tile2(A, row0, lda, k0, s, tid, 128);
        stage_tile2(B, col0, ldb, k0, s + ASLOT, tid, 256);
    };

    const int NIT = K >> 5;
    stage_set(0, 0);
    stage_set(1, 32);
    int bufs = 2, bufr = 0;
    for (int t = 0; t < NIT; ++t){
        if (t + 2 < NIT){ stage_set(bufs, (t + 2) << 5); bufs = (bufs + 1 == 3) ? 0 : bufs + 1; }
        const int rem = NIT - 1 - t;
        if (rem >= 2)      asm volatile("s_waitcnt vmcnt(12)" ::: "memory");
        else if (rem == 1) asm volatile("s_waitcnt vmcnt(6)" ::: "memory");
        else               asm volatile("s_waitcnt vmcnt(0)" ::: "memory");
        __builtin_amdgcn_s_barrier();
        __builtin_amdgcn_sched_barrier(0);

        const u16* s = sh + bufr * SLOT;
        bufr = (bufr + 1 == 3) ? 0 : bufr + 1;

        half8 a[4], b[8];
#pragma unroll
        for (int m = 0; m < 4; m++) a[m] = *(const half8*)&s[(wr + m * 16 + lr) * 32 + co];
#pragma unroll
        for (int n = 0; n < 8; n++) b[n] = *(const half8*)&s[ASLOT + (wc + n * 16 + lr) * 32 + co];
#pragma unroll
        for (int m = 0; m < 4; m++)
#pragma unroll
            for (int n = 0; n < 8; n++)
                acc[m][n] = __builtin_amdgcn_mfma_f32_16x16x32_f16(a[m], b[n], acc[m][n], 0, 0, 0);
        __builtin_amdgcn_sched_barrier(0);
        __builtin_amdgcn_s_barrier();
    }

#pragma unroll
    for (int m = 0; m < 4; m++) {
        const int rb = row0 + wr + m * 16 + hi * 4;
#pragma unroll
        for (int n = 0; n < 8; n++) {
            const int c = col0 + wc + n * 16 + lr;
#pragma unroll
            for (int q = 0; q < 4; q++)
                of[(size_t)(rb + q) * ldc + c] = acc[m][n][q];
        }
    }
}

__global__ __launch_bounds__(256, 2) void av_k(
    const u16* __restrict__ W_h, const u16* __restrict__ Vt, float* __restrict__ outp)
{
    __shared__ __align__(16) u16 sh[3 * SLOT];   // 72KB
    const int nwg = gridDim.x, chunk = nwg >> 3;
    const int wg = ((int)blockIdx.x & 7) * chunk + ((int)blockIdx.x >> 3);
    const int z = wg >> 5, rem = wg & 31;        // by<8, bx<4
    gemm_core2(W_h + ((size_t)z << 20), Vt + (size_t)z * 1024,
               outp + ((size_t)z << 20),
               rem >> 2, rem & 3, 1024, 8192, 1024, 1024, sh);
}

// ========================= small kernels ====================================
__global__ __launch_bounds__(256)
void colmean_k(const u16* __restrict__ ri_h, float* __restrict__ xbar)
{
    const int b = blockIdx.x >> 5, sub = blockIdx.x & 31;
    const int dg = sub & 3, rg = sub >> 2;
    const int d = dg * 256 + threadIdx.x;
    const u16* base = ri_h + ((size_t)b << 20) + ((size_t)(rg * 128) << 10) + d;
    float s = 0.f;
#pragma unroll 4
    for (int r = 0; r < 128; ++r) s += h2f(base[(size_t)r << 10]);
    atomicAdd(&xbar[(b << 10) + d], s * (1.f / 1024.f));
}

template<bool BIAS, bool AFULL>
__global__ __launch_bounds__(256)
void rowdot_k(const u16* __restrict__ A, const float* __restrict__ B,
              const float* __restrict__ bias, float* __restrict__ out)
{
    const int o = blockIdx.x * 4 + (threadIdx.x >> 6);
    const int lane = threadIdx.x & 63;
    const int ar = AFULL ? o : (o & 1023);
    const int br = o >> 10;
    const u16* ap = A + ((size_t)ar << 10);
    const float* bp = B + ((size_t)br << 10);
    float s = 0.f;
#pragma unroll
    for (int j = 0; j < 16; ++j){ const int i = lane + (j << 6); s += h2f(ap[i]) * bp[i]; }
#pragma unroll
    for (int off = 32; off >= 1; off >>= 1) s += __shfl_xor(s, off);
    if (lane == 0) out[o] = s + (BIAS ? bias[ar] : 0.f);
}

__global__ __launch_bounds__(256)
void softmax_scale_k(float* __restrict__ W, const u16* __restrict__ Kd,
                     const u16* __restrict__ Krs, const float* __restrict__ cm,
                     u16* __restrict__ Wh)
{
    const long row = blockIdx.x;
    const int b = (int)(row >> 10);
    float* p = W + (row << 10);
    const int tid = threadIdx.x;

    float4 v = ((const float4*)p)[tid];
    const ushort4 kd = ((const ushort4*)(Kd + (row << 10)))[tid];
    const ushort4 ks = ((const ushort4*)(Krs + (row << 10)))[tid];
    const float4 cmv = ((const float4*)(cm + ((size_t)b << 10)))[tid];
    v.x *= rsqrtf(h2f(kd.x) + h2f(ks.x) + cmv.x);
    v.y *= rsqrtf(h2f(kd.y) + h2f(ks.y) + cmv.y);
    v.z *= rsqrtf(h2f(kd.z) + h2f(ks.z) + cmv.z);
    v.w *= rsqrtf(h2f(kd.w) + h2f(ks.w) + cmv.w);

    float m = fmaxf(fmaxf(v.x, v.y), fmaxf(v.z, v.w));
#pragma unroll
    for (int o = 32; o >= 1; o >>= 1) m = fmaxf(m, __shfl_xor(m, o));
    __shared__ float sm[4];
    const int wid = tid >> 6, lane = tid & 63;
    if (lane == 0) sm[wid] = m;
    __syncthreads();
    m = fmaxf(fmaxf(sm[0], sm[1]), fmaxf(sm[2], sm[3]));

    v.x = __expf(v.x - m); v.y = __expf(v.y - m);
    v.z = __expf(v.z - m); v.w = __expf(v.w - m);
    float s = v.x + v.y + v.z + v.w;
#pragma unroll
    for (int o = 32; o >= 1; o >>= 1) s += __shfl_xor(s, o);
    __shared__ float ss[4];
    if (lane == 0) ss[wid] = s;
    __syncthreads();
    s = ss[0] + ss[1] + ss[2] + ss[3];

    const float inv = 1.0f / s;
    v.x *= inv; v.y *= inv; v.z *= inv; v.w *= inv;
    ((float4*)p)[tid] = v;

    ushort4 ub;
    ub.x = f2h(v.x); ub.y = f2h(v.y); ub.z = f2h(v.z); ub.w = f2h(v.w);
    ((ushort4*)(Wh + (row << 10)))[tid] = ub;
}

__global__ __launch_bounds__(256)
void conv_plain5_k(const float4* __restrict__ x0, ushort4* __restrict__ y0,
                   const float4* __restrict__ x1, ushort4* __restrict__ y1,
                   const float4* __restrict__ x2, ushort4* __restrict__ y2,
                   const float4* __restrict__ x3, ushort4* __restrict__ y3,
                   const float4* __restrict__ x4, ushort4* __restrict__ y4)
{
    const long i = (long)blockIdx.x * 256 + threadIdx.x;
    const long n0 = 2097152, n1 = 262144;
    const float4* x; ushort4* y; long j;
    if (i < n0)                 { x = x0; y = y0; j = i; }
    else if (i < 2*n0)          { x = x1; y = y1; j = i - n0; }
    else if (i < 2*n0 + n1)     { x = x2; y = y2; j = i - 2*n0; }
    else if (i < 2*n0 + 2*n1)   { x = x3; y = y3; j = i - 2*n0 - n1; }
    else                        { x = x4; y = y4; j = i - 2*n0 - 2*n1; }
    const float4 v = x[j];
    ushort4 o;
    o.x = f2h(v.x); o.y = f2h(v.y); o.z = f2h(v.z); o.w = f2h(v.w);
    y[j] = o;
}

extern "C" void kernel_launch(void* const* d_in, const int* in_sizes, int n_in,
                              void* d_out, int out_size, void* d_ws, size_t ws_size,
                              hipStream_t stream)
{
    const float* rc = (const float*)d_in[0];
    const float* ri = (const float*)d_in[1];
    const float* Wq = (const float*)d_in[3];
    const float* bq = (const float*)d_in[4];
    const float* Wk = (const float*)d_in[5];
    const float* bk = (const float*)d_in[6];
    const float* Wv = (const float*)d_in[7];
    const float* bv = (const float*)d_in[8];

    const long M8 = 8192 * 1024L;
    const long M1 = 1024 * 1024L;

    u16* ws   = (u16*)d_ws;
    u16* ri_h = ws;                  // 8M; reused as W_h after softmax
    u16* rc_h = ws + 1 * M8;         // 8M; reused as Vt after lin_qk
    u16* Kd   = ws + 2 * M8;         // 8M
    u16* Krs  = ws + 3 * M8;         // 8M
    u16* Wq_h = ws + 4 * M8;         // 1M
    u16* Wk_h = Wq_h + M1;           // 1M
    u16* Wv_h = Wk_h + M1;           // 1M
    float* xbar = (float*)(ws + 4 * M8 + 3 * M1);
    float* cm   = xbar + 8192;
    float* uu   = cm + 8192;

    float* outp = (float*)d_out;
    float* wts  = outp + M8;
    u16*   Q_h  = (u16*)d_out;       // scratch in outp half, dead before AV
    u16*   Vt   = rc_h;              // V^T [1024][8192]
    u16*   W_h  = ri_h;

    conv_plain5_k<<<19456, 256, 0, stream>>>(
        (const float4*)ri, (ushort4*)ri_h, (const float4*)rc, (ushort4*)rc_h,
        (const float4*)Wq, (ushort4*)Wq_h, (const float4*)Wk, (ushort4*)Wk_h,
        (const float4*)Wv, (ushort4*)Wv_h);

    hipMemsetAsync(xbar, 0, 8192 * sizeof(float), stream);
    colmean_k<<<256, 256, 0, stream>>>(ri_h, xbar);
    rowdot_k<true, false><<<2048, 256, 0, stream>>>(Wk_h, xbar, bk, cm);

    // Q + K linears, 8-phase: 256 blocks x 512 thr (grid congruent with qkt_vt)
    lin_qk_k<<<256, 512, 0, stream>>>(rc_h, ri_h, Wq_h, Wk_h, bq, bk, cm, Q_h, Kd, Krs);

    rowdot_k<false, true><<<2048, 256, 0, stream>>>(Q_h, cm, nullptr, uu);

    // centered QK^T + V^T, 8-phase: 256 blocks x 512 thr
    qkt_vt_k<<<256, 512, 0, stream>>>(Q_h, Kd, ri_h, Wv_h, bv, uu, wts, Vt);

    softmax_scale_k<<<8192, 256, 0, stream>>>(wts, Kd, Krs, cm, W_h);

    // AV stays 2-phase
    av_k<<<256, 256, 0, stream>>>(W_h, Vt, outp);
}